// Round 8
// baseline (236.429 us; speedup 1.0000x reference)
//
#include <hip/hip_runtime.h>
#include <hip/hip_bf16.h>

#define NN 50000
#define EE 800000
#define DD 128
#define HH 4
#define NEG_SLOPE 0.2f

#define BSH 9                 // bucket = dst >> 9 (512 dsts)
#define NBUCK 98              // ceil(50000/512)
#define CH 8192               // edges per chunk
#define NBLK 98               // ceil(800000/8192)
#define NSEG (2 * NBUCK * NBLK)   // 19208 flat scan cells
#define BKB (2 * NBLK)        // 196 bucket blocks
#define SORTB (2 * NBUCK)     // 196 sort blocks
#define ELRB 3125             // 50000/16 rows-per-block
#define PJB ((NN + 127) / 128)    // 391 proj blocks
#define WB 192                // wcvt blocks

typedef __attribute__((ext_vector_type(8))) short bf16x8;
typedef __attribute__((ext_vector_type(4))) float f32x4;
typedef __attribute__((ext_vector_type(8))) unsigned short ushrt8;

static __device__ __forceinline__ float bf2f(ushort u) {
    union { unsigned int ui; float f; } v; v.ui = ((unsigned int)u) << 16; return v.f;
}
static __device__ __forceinline__ void split1(float v, ushort& h, ushort& l) {
    __hip_bfloat16 hb = __float2bfloat16(v);
    float hf = __bfloat162float(hb);
    __hip_bfloat16 lb = __float2bfloat16(v - hf);
    h = *(ushort*)&hb; l = *(ushort*)&lb;
}

// ---------------- prep: wcvt (192) + hist (196) + uvec (1) --------------------
// wt layout: 12 chunks (m*4+kc) of 16KB: [n=128][slot'=8][8 ushorts],
// slot = hl*4 + kin8, slot' = slot ^ (n&7)  -- swizzle baked in for LDS.
// uvec[v][k], v = rel*8 + lr*4 + h: u = sum_d W[k][h*32+d]*attn[h][d].
__global__ __launch_bounds__(256) void prep_kernel(
    const float* __restrict__ W0, const float* __restrict__ W1,
    const float* __restrict__ Wl,
    const float* __restrict__ al0, const float* __restrict__ ar0,
    const float* __restrict__ al1, const float* __restrict__ ar1,
    const int* __restrict__ dst0, const int* __restrict__ dst1,
    ushort* __restrict__ wt, float* __restrict__ uvec, int* __restrict__ hist)
{
    const int b = blockIdx.x;
    const int t = threadIdx.x;
    if (b < WB) {                                  // W -> pre-swizzled chunks
        int idx = b * 256 + t;                     // 0..49151
        int m = idx >> 14, e = idx & 16383;
        const float* W = (m == 0) ? W0 : (m == 1) ? W1 : Wl;
        int k = e >> 7, n = e & 127;               // W[k][n]
        ushort h, l; split1(W[e], h, l);
        int q = m * 4 + (k >> 5);
        int kin8 = (k >> 3) & 3, ke = k & 7;
        int sw = n & 7;
        size_t base = (size_t)q * 8192 + n * 64;
        wt[base + (((0 | kin8) ^ sw) << 3) + ke] = h;
        wt[base + (((4 | kin8) ^ sw) << 3) + ke] = l;
    } else if (b < WB + BKB) {                     // per-chunk bucket histogram
        __shared__ int cnt[NBUCK];
        int hb = b - WB;                           // 0..195
        int rel = hb >= NBLK;
        int ci = hb - rel * NBLK;
        const int* __restrict__ dstA = rel ? dst1 : dst0;
        if (t < NBUCK) cnt[t] = 0;
        __syncthreads();
        int lo = ci * CH, hi = min(lo + CH, EE);
        for (int i = lo + t; i < hi; i += 256)
            atomicAdd(&cnt[dstA[i] >> BSH], 1);
        __syncthreads();
        if (t < NBUCK)
            hist[((rel * NBUCK) + t) * NBLK + ci] = cnt[t];
    } else {                                       // uvec: 2048 entries
        #pragma unroll
        for (int j = 0; j < 8; ++j) {
            int idx = t * 8 + j;
            int v = idx >> 7, k = idx & 127;
            int rel = v >> 3, lr = (v >> 2) & 1, h = v & 3;
            const float* W = rel ? W1 : W0;
            const float* a = rel ? (lr ? ar1 : al1) : (lr ? ar0 : al0);
            float s = 0.f;
            for (int d2 = 0; d2 < 32; ++d2)
                s += W[k * 128 + h * 32 + d2] * a[h * 32 + d2];
            uvec[v * 128 + k] = s;
        }
    }
}

// ---------------- flat exclusive scan of hist -> base -------------------------
__global__ __launch_bounds__(256) void scan_kernel(
    const int* __restrict__ hist, int* __restrict__ base)
{
    __shared__ int wq[4];
    const int t = threadIdx.x;
    const int lane = t & 63, wv = t >> 6;
    const int st = t * 76;
    const int en = min(st + 76, NSEG);
    int sum = 0;
    for (int i = st; i < en; ++i) sum += hist[i];
    int incl = sum;
    #pragma unroll
    for (int off = 1; off < 64; off <<= 1) {
        int u = __shfl_up(incl, off);
        if (lane >= off) incl += u;
    }
    if (lane == 63) wq[wv] = incl;
    __syncthreads();
    int woff = 0;
    #pragma unroll
    for (int w = 0; w < 4; ++w) woff += (w < wv) ? wq[w] : 0;
    int run = woff + incl - sum;                   // exclusive prefix
    for (int i = st; i < en; ++i) { base[i] = run; run += hist[i]; }
}

// ---------------- fused: bucket scatter (0..195) + elr (196..3320) ------------
__global__ __launch_bounds__(256) void bucketelr_kernel(
    const int* __restrict__ src0, const int* __restrict__ dst0,
    const int* __restrict__ src1, const int* __restrict__ dst1,
    const int* __restrict__ base, unsigned int* __restrict__ pk,
    const float* __restrict__ x, const float* __restrict__ uvec,
    float* __restrict__ el0, float* __restrict__ er0,
    float* __restrict__ el1, float* __restrict__ er1)
{
    __shared__ float sm[2048];                    // elr: uvec copy; bucket: ints
    const int t = threadIdx.x;

    if (blockIdx.x < BKB) {
        // ------------- bucket scatter -------------
        int* cnt = (int*)sm;
        int* bs  = cnt + 128;
        const int hb = blockIdx.x;
        const int rel = hb >= NBLK;
        const int ci = hb - rel * NBLK;
        const int* __restrict__ srcA = rel ? src1 : src0;
        const int* __restrict__ dstA = rel ? dst1 : dst0;
        if (t < NBUCK) {
            cnt[t] = 0;
            bs[t] = base[((rel * NBUCK) + t) * NBLK + ci];
        }
        __syncthreads();
        int lo = ci * CH, hi = min(lo + CH, EE);
        for (int i = lo + t; i < hi; i += 256) {
            int dd = dstA[i], ss = srcA[i];
            int bk = dd >> BSH;
            int rk = atomicAdd(&cnt[bk], 1);
            pk[bs[bk] + rk] = (unsigned int)ss | ((unsigned int)(dd & 511) << 17);
        }
        return;
    }

    // ------------- elr: el/er = x . uvec -------------
    for (int i = t; i < 2048; i += 256) sm[i] = uvec[i];
    __syncthreads();
    const int lane = t & 63, wave = t >> 6;
    const int l16 = lane & 15;
    const int r = (blockIdx.x - BKB) * 16 + wave * 4 + (lane >> 4);
    float xr[8];
    if (r < NN) {
        float4 a = *(const float4*)&x[(size_t)r * DD + l16 * 8];
        float4 b2 = *(const float4*)&x[(size_t)r * DD + l16 * 8 + 4];
        xr[0] = a.x; xr[1] = a.y; xr[2] = a.z; xr[3] = a.w;
        xr[4] = b2.x; xr[5] = b2.y; xr[6] = b2.z; xr[7] = b2.w;
    } else {
        #pragma unroll
        for (int j = 0; j < 8; ++j) xr[j] = 0.f;
    }
    float s[16];
    #pragma unroll
    for (int v = 0; v < 16; ++v) {
        float acc = 0.f;
        const float* u = &sm[v * 128 + l16 * 8];
        #pragma unroll
        for (int j = 0; j < 8; ++j) acc += xr[j] * u[j];
        s[v] = acc;
    }
    #pragma unroll
    for (int m = 1; m < 16; m <<= 1)
        #pragma unroll
        for (int v = 0; v < 16; ++v) s[v] += __shfl_xor(s[v], m);
    if (r < NN) {
        float val = s[0];
        #pragma unroll
        for (int v = 1; v < 16; ++v) val = (l16 == v) ? s[v] : val;
        float* p = (l16 & 8) ? ((l16 & 4) ? er1 : el1)
                             : ((l16 & 4) ? er0 : el0);
        p[(size_t)r * 4 + (l16 & 3)] = val;
    }
}

// ---------------- fused: sort+softmax (0..195) + proj (196..586) --------------
__global__ __launch_bounds__(256) void projsort_kernel(
    const unsigned int* __restrict__ pk, const int* __restrict__ base,
    const float* __restrict__ el0, const float* __restrict__ er0,
    const float* __restrict__ el1, const float* __restrict__ er1,
    float* __restrict__ wbuf,
    int* __restrict__ row0, int* __restrict__ row1,
    int* __restrict__ list, float* __restrict__ alphaAll,
    const float* __restrict__ x, const ushort* __restrict__ wt,
    const float* __restrict__ bias,
    ushort* __restrict__ fb0, ushort* __restrict__ fb1,
    float* __restrict__ out)
{
    __shared__ ushort lds[2][8192];               // proj: 2x16KB; sort aliases
    const int t = threadIdx.x;

    if (blockIdx.x < SORTB) {
        // ------------- per-bucket counting sort + softmax -------------
        float* er_s = (float*)&lds[0][0];         // 2048 f (8KB)
        float* den  = er_s + 2048;                // 2048 f (8KB)
        int* cnt    = (int*)(den + 2048);         // 512
        int* offs   = cnt + 512;                  // 512
        int* wq     = offs + 512;                 // 4
        const int hb = blockIdx.x;
        const int lane = t & 63, wv = t >> 6;
        const int rel = hb >= NBUCK;
        const int bk = hb - rel * NBUCK;
        const int fs = base[((rel * NBUCK) + bk) * NBLK];
        const int fe = (rel == 1 && bk == NBUCK - 1) ? 2 * EE
                     : base[((rel * NBUCK) + bk + 1) * NBLK];
        const float* __restrict__ elA = rel ? el1 : el0;
        const float* __restrict__ erA = rel ? er1 : er0;
        const int d0 = bk << BSH;

        for (int j = t; j < 512; j += 256) {
            int d = d0 + j;
            float4 e = make_float4(0.f, 0.f, 0.f, 0.f);
            if (d < NN) e = *(const float4*)&erA[(size_t)d * 4];
            *(float4*)&er_s[j * 4] = e;
            *(float4*)&den[j * 4] = make_float4(0.f, 0.f, 0.f, 0.f);
            cnt[j] = 0;
        }
        __syncthreads();

        for (int i = fs + t; i < fe; i += 256) {  // P1: w + den + cnt
            unsigned int u = pk[i];
            int s = u & 0x1FFFF, ld = u >> 17;
            atomicAdd(&cnt[ld], 1);
            float4 e = *(const float4*)&elA[(size_t)s * 4];
            float4 rr = *(const float4*)&er_s[ld * 4];
            float4 w;
            float v;
            v = e.x + rr.x; v = v > 0.f ? v : NEG_SLOPE * v; w.x = __expf(v);
            v = e.y + rr.y; v = v > 0.f ? v : NEG_SLOPE * v; w.y = __expf(v);
            v = e.z + rr.z; v = v > 0.f ? v : NEG_SLOPE * v; w.z = __expf(v);
            v = e.w + rr.w; v = v > 0.f ? v : NEG_SLOPE * v; w.w = __expf(v);
            *(float4*)&wbuf[(size_t)i * 4] = w;
            atomicAdd(&den[ld * 4 + 0], w.x);
            atomicAdd(&den[ld * 4 + 1], w.y);
            atomicAdd(&den[ld * 4 + 2], w.z);
            atomicAdd(&den[ld * 4 + 3], w.w);
        }
        __syncthreads();

        int a = cnt[2 * t], bvl = cnt[2 * t + 1]; // P2: scan 512 counts
        int ps = a + bvl;
        int incl = ps;
        #pragma unroll
        for (int off = 1; off < 64; off <<= 1) {
            int u = __shfl_up(incl, off);
            if (lane >= off) incl += u;
        }
        if (lane == 63) wq[wv] = incl;
        __syncthreads();
        int woff = 0;
        #pragma unroll
        for (int w = 0; w < 4; ++w) woff += (w < wv) ? wq[w] : 0;
        int excl = woff + incl - ps;
        offs[2 * t] = excl;
        offs[2 * t + 1] = excl + a;
        __syncthreads();

        int* __restrict__ row = rel ? row1 : row0;
        const int fsLocal = fs - (rel ? EE : 0);
        for (int j = t; j < 512; j += 256) {      // CSR row ends
            int d = d0 + j;
            if (d < NN) row[d] = fsLocal + offs[j] + cnt[j];
        }
        for (int j = t; j < 2048; j += 256)       // den -> 1/den
            den[j] = 1.f / den[j];
        __syncthreads();

        for (int i = fs + t; i < fe; i += 256) {  // P3: scatter src + alpha
            unsigned int u = pk[i];
            int s = u & 0x1FFFF, ld = u >> 17;
            int p = atomicAdd(&offs[ld], 1);
            float4 w = *(const float4*)&wbuf[(size_t)i * 4];
            float4 dn = *(const float4*)&den[ld * 4];
            float4 al4 = make_float4(w.x * dn.x, w.y * dn.y, w.z * dn.z, w.w * dn.w);
            list[fs + p] = s;
            *(float4*)&alphaAll[(size_t)(fs + p) * 4] = al4;
        }
        return;
    }

    // ------------- proj: x-direct MFMA, LDS-staged W -------------
    const int pb = blockIdx.x - SORTB;
    const int lane = t & 63, wave = t >> 6;
    const int l15 = lane & 15, lg = lane >> 4;
    const int rb = pb * 128 + wave * 32;

    int ra0 = rb + l15;      if (ra0 > NN - 1) ra0 = NN - 1;
    int ra1 = rb + 16 + l15; if (ra1 > NN - 1) ra1 = NN - 1;
    const int kb = lg * 8;

    // A fragments: load x f32, split to (hi,lo) bf16 in-register
    bf16x8 Ah0[4], Av0[4], Ah1[4], Av1[4];
    #pragma unroll
    for (int kc = 0; kc < 4; ++kc) {
        const float* p0 = &x[(size_t)ra0 * DD + kc * 32 + kb];
        const float* p1 = &x[(size_t)ra1 * DD + kc * 32 + kb];
        float4 f0a = *(const float4*)p0, f0b = *(const float4*)(p0 + 4);
        float4 f1a = *(const float4*)p1, f1b = *(const float4*)(p1 + 4);
        float t0[8] = {f0a.x, f0a.y, f0a.z, f0a.w, f0b.x, f0b.y, f0b.z, f0b.w};
        float t1[8] = {f1a.x, f1a.y, f1a.z, f1a.w, f1b.x, f1b.y, f1b.z, f1b.w};
        union { bf16x8 v; ushort u[8]; } H0, L0, H1, L1;
        #pragma unroll
        for (int j = 0; j < 8; ++j) {
            split1(t0[j], H0.u[j], L0.u[j]);
            split1(t1[j], H1.u[j], L1.u[j]);
        }
        Ah0[kc] = H0.v; Av0[kc] = L0.v;
        Ah1[kc] = H1.v; Av1[kc] = L1.v;
    }

    {   // prologue: stage chunk 0 into lds[0]
        const bf16x8* g = (const bf16x8*)wt;
        bf16x8* L = (bf16x8*)lds[0];
        #pragma unroll
        for (int i = 0; i < 4; ++i) L[t + i * 256] = g[t + i * 256];
    }

    for (int m = 0; m < 3; ++m) {
        f32x4 acc0[8], acc1[8];
        #pragma unroll
        for (int nt = 0; nt < 8; ++nt) {
            acc0[nt] = (f32x4){0.f, 0.f, 0.f, 0.f};
            acc1[nt] = (f32x4){0.f, 0.f, 0.f, 0.f};
        }

        #pragma unroll
        for (int kc = 0; kc < 4; ++kc) {
            const int q = m * 4 + kc;
            __syncthreads();
            bf16x8 st0, st1, st2, st3;
            const bool hasNext = (q < 11);
            if (hasNext) {
                const bf16x8* g = (const bf16x8*)(wt + (size_t)(q + 1) * 8192);
                st0 = g[t]; st1 = g[t + 256]; st2 = g[t + 512]; st3 = g[t + 768];
            }
            const ushort* __restrict__ L = lds[kc & 1];
            #pragma unroll
            for (int nt = 0; nt < 8; ++nt) {
                const int n = nt * 16 + l15;
                const int sw = n & 7;
                bf16x8 bh = *(const bf16x8*)&L[n * 64 + (((0 | lg) ^ sw) << 3)];
                bf16x8 bv = *(const bf16x8*)&L[n * 64 + (((4 | lg) ^ sw) << 3)];
                acc0[nt] = __builtin_amdgcn_mfma_f32_16x16x32_bf16(Ah0[kc], bh, acc0[nt], 0, 0, 0);
                acc0[nt] = __builtin_amdgcn_mfma_f32_16x16x32_bf16(Ah0[kc], bv, acc0[nt], 0, 0, 0);
                acc0[nt] = __builtin_amdgcn_mfma_f32_16x16x32_bf16(Av0[kc], bh, acc0[nt], 0, 0, 0);
                acc1[nt] = __builtin_amdgcn_mfma_f32_16x16x32_bf16(Ah1[kc], bh, acc1[nt], 0, 0, 0);
                acc1[nt] = __builtin_amdgcn_mfma_f32_16x16x32_bf16(Ah1[kc], bv, acc1[nt], 0, 0, 0);
                acc1[nt] = __builtin_amdgcn_mfma_f32_16x16x32_bf16(Av1[kc], bh, acc1[nt], 0, 0, 0);
            }
            if (hasNext) {
                bf16x8* Lw = (bf16x8*)lds[(kc & 1) ^ 1];
                Lw[t] = st0; Lw[t + 256] = st1; Lw[t + 512] = st2; Lw[t + 768] = st3;
            }
        }

        if (m < 2) {                               // feat -> bf16 tables
            ushort* __restrict__ fb = m ? fb1 : fb0;
            #pragma unroll
            for (int tt = 0; tt < 2; ++tt)
                #pragma unroll
                for (int nt = 0; nt < 8; ++nt) {
                    const int col = nt * 16 + l15;
                    #pragma unroll
                    for (int r = 0; r < 4; ++r) {
                        const int row = rb + tt * 16 + lg * 4 + r;
                        const float v = tt ? acc1[nt][r] : acc0[nt][r];
                        if (row < NN) {
                            __hip_bfloat16 hb = __float2bfloat16(v);
                            fb[(size_t)row * DD + col] = *(ushort*)&hb;
                        }
                    }
                }
        } else {                                   // out = x@Wl + bias
            #pragma unroll
            for (int tt = 0; tt < 2; ++tt)
                #pragma unroll
                for (int nt = 0; nt < 8; ++nt) {
                    const int col = nt * 16 + l15;
                    const float bv = bias[col];
                    #pragma unroll
                    for (int r = 0; r < 4; ++r) {
                        const int row = rb + tt * 16 + lg * 4 + r;
                        const float v = tt ? acc1[nt][r] : acc0[nt][r];
                        if (row < NN) out[(size_t)row * DD + col] = v + bv;
                    }
                }
        }
    }
}

// ---------------- aggregate: pure alpha-weighted gather -----------------------
__global__ __launch_bounds__(256) void agg_kernel(
    const int* __restrict__ row0, const int* __restrict__ list0,
    const int* __restrict__ row1, const int* __restrict__ list1,
    const float* __restrict__ alphaAll,
    const ushort* __restrict__ fb0, const ushort* __restrict__ fb1,
    float* __restrict__ out)
{
    const int d = blockIdx.x * 4 + (threadIdx.x >> 6);
    const int lane = threadIdx.x & 63;
    if (d >= NN) return;
    const int g = lane >> 4;             // 4 edge slots, 2-deep pipeline
    const int l16 = lane & 15;
    const int c = l16 * 8;               // 8 output cols per lane
    const int h = l16 >> 2;              // head = col>>5

    float tot[8] = {0.f, 0.f, 0.f, 0.f, 0.f, 0.f, 0.f, 0.f};

    #pragma unroll
    for (int rel = 0; rel < 2; ++rel) {
        const int* __restrict__ rowA = rel ? row1 : row0;
        const int* __restrict__ lst  = rel ? list1 : list0;
        const ushort* __restrict__ fbA = rel ? fb1 : fb0;
        const size_t ab = rel ? (size_t)EE : 0;

        const int s0 = d ? rowA[d - 1] : 0, e0 = rowA[d];
        float acc[8] = {0.f, 0.f, 0.f, 0.f, 0.f, 0.f, 0.f, 0.f};

        int i = s0 + g;
        float aA = 0.f;
        ushrt8 fA = (ushrt8){0, 0, 0, 0, 0, 0, 0, 0};
        if (i < e0) {
            int s = lst[i];
            aA = alphaAll[(ab + (size_t)i) * 4 + h];
            fA = *(const ushrt8*)&fbA[(size_t)s * DD + c];
        }
        while (i < e0) {
            const int inext = i + 4;
            float aB = 0.f;
            ushrt8 fB = (ushrt8){0, 0, 0, 0, 0, 0, 0, 0};
            if (inext < e0) {
                int s = lst[inext];
                aB = alphaAll[(ab + (size_t)inext) * 4 + h];
                fB = *(const ushrt8*)&fbA[(size_t)s * DD + c];
            }
            #pragma unroll
            for (int q = 0; q < 8; ++q) acc[q] += aA * bf2f(fA[q]);
            i = inext; aA = aB; fA = fB;
        }

        #pragma unroll
        for (int q = 0; q < 8; ++q) {
            acc[q] += __shfl_xor(acc[q], 16);
            acc[q] += __shfl_xor(acc[q], 32);
            tot[q] += acc[q];
        }
    }

    if (g == 0) {
        float4 o1 = *(float4*)&out[(size_t)d * DD + c];
        float4 o2 = *(float4*)&out[(size_t)d * DD + c + 4];
        o1.x = fmaxf(o1.x + tot[0], 0.f); o1.y = fmaxf(o1.y + tot[1], 0.f);
        o1.z = fmaxf(o1.z + tot[2], 0.f); o1.w = fmaxf(o1.w + tot[3], 0.f);
        o2.x = fmaxf(o2.x + tot[4], 0.f); o2.y = fmaxf(o2.y + tot[5], 0.f);
        o2.z = fmaxf(o2.z + tot[6], 0.f); o2.w = fmaxf(o2.w + tot[7], 0.f);
        *(float4*)&out[(size_t)d * DD + c] = o1;
        *(float4*)&out[(size_t)d * DD + c + 4] = o2;
    }
}

extern "C" void kernel_launch(void* const* d_in, const int* in_sizes, int n_in,
                              void* d_out, int out_size, void* d_ws, size_t ws_size,
                              hipStream_t stream)
{
    const float* x    = (const float*)d_in[0];
    const float* W0   = (const float*)d_in[1];
    const float* al0  = (const float*)d_in[2];
    const float* ar0  = (const float*)d_in[3];
    const float* W1   = (const float*)d_in[4];
    const float* al1  = (const float*)d_in[5];
    const float* ar1  = (const float*)d_in[6];
    const float* Wl   = (const float*)d_in[7];
    const float* bias = (const float*)d_in[8];
    const int* src0   = (const int*)d_in[9];
    const int* dst0   = (const int*)d_in[10];
    const int* src1   = (const int*)d_in[11];
    const int* dst1   = (const int*)d_in[12];
    float* out = (float*)d_out;

    // workspace layout (4-byte units)
    float* wsf      = (float*)d_ws;
    float* wbuf     = wsf;                            // 2E*4 f32 = 25.6MB
    float* alphaAll = wbuf + (size_t)8 * EE;          // 2E*4 f32 = 25.6MB
    ushort* fb0 = (ushort*)(alphaAll + (size_t)8 * EE);
    ushort* fb1 = fb0 + (size_t)NN * DD;
    ushort* wt  = fb1 + (size_t)NN * DD;              // 12*8192 ushorts
    float* uvec = (float*)(wt + 12 * 8192);           // 2048 f32
    float* el0  = uvec + 2048;
    float* er0  = el0 + (size_t)NN * HH;
    float* el1  = er0 + (size_t)NN * HH;
    float* er1  = el1 + (size_t)NN * HH;
    int* hist   = (int*)(er1 + (size_t)NN * HH);
    int* base   = hist + NSEG;
    int* row0   = base + NSEG;
    int* row1   = row0 + NN;
    unsigned int* pk = (unsigned int*)(row1 + NN);    // 2*E
    int* list   = (int*)(pk + (size_t)2 * EE);        // 2*E
    int* list0  = list;
    int* list1  = list + EE;

    prep_kernel<<<dim3(WB + BKB + 1), dim3(256), 0, stream>>>(
        W0, W1, Wl, al0, ar0, al1, ar1, dst0, dst1, wt, uvec, hist);

    scan_kernel<<<dim3(1), dim3(256), 0, stream>>>(hist, base);

    bucketelr_kernel<<<dim3(BKB + ELRB), dim3(256), 0, stream>>>(
        src0, dst0, src1, dst1, base, pk, x, uvec, el0, er0, el1, er1);

    projsort_kernel<<<dim3(SORTB + PJB), dim3(256), 0, stream>>>(
        pk, base, el0, er0, el1, er1, wbuf, row0, row1, list, alphaAll,
        x, wt, bias, fb0, fb1, out);

    agg_kernel<<<dim3((NN + 3) / 4), dim3(256), 0, stream>>>(
        row0, list0, row1, list1, alphaAll, fb0, fb1, out);
}

// Round 9
// 193.858 us; speedup vs baseline: 1.2196x; 1.2196x over previous
//
#include <hip/hip_runtime.h>
#include <hip/hip_bf16.h>

#define NN 50000
#define EE 800000
#define DD 128
#define HH 4
#define NEG_SLOPE 0.2f

#define BSH 9                 // bucket = dst >> 9 (512 dsts)
#define NBUCK 98              // ceil(50000/512)
#define CH 8192               // edges per chunk
#define NBLK 98               // ceil(800000/8192)
#define NSEG (2 * NBUCK * NBLK)   // 19208 flat scan cells
#define BKB (2 * NBLK)        // 196 bucket blocks
#define SORTB (2 * NBUCK)     // 196 sort blocks
#define ELRB 3125             // 50000/16 rows per block
#define PJB ((NN + 127) / 128)    // 391 proj blocks
#define WB 192                // wcvt blocks

typedef __attribute__((ext_vector_type(8))) short bf16x8;
typedef __attribute__((ext_vector_type(4))) float f32x4;
typedef __attribute__((ext_vector_type(8))) unsigned short ushrt8;

static __device__ __forceinline__ float bf2f(ushort u) {
    union { unsigned int ui; float f; } v; v.ui = ((unsigned int)u) << 16; return v.f;
}
static __device__ __forceinline__ void split1(float v, ushort& h, ushort& l) {
    __hip_bfloat16 hb = __float2bfloat16(v);
    float hf = __bfloat162float(hb);
    __hip_bfloat16 lb = __float2bfloat16(v - hf);
    h = *(ushort*)&hb; l = *(ushort*)&lb;
}

// ---------------- prep: wcvt (192) + hist (196) + uvec (1) --------------------
// wt layout: 12 chunks (m*4+kc) of 16KB: [n=128][slot'=8][8 ushorts],
// slot = hl*4 + kin8, slot' = slot ^ (n&7)  -- swizzle baked in for LDS.
// uvec[v][k], v = rel*8 + lr*4 + h: u = sum_d W[k][h*32+d]*attn[h][d].
__global__ __launch_bounds__(256) void prep_kernel(
    const float* __restrict__ W0, const float* __restrict__ W1,
    const float* __restrict__ Wl,
    const float* __restrict__ al0, const float* __restrict__ ar0,
    const float* __restrict__ al1, const float* __restrict__ ar1,
    const int* __restrict__ dst0, const int* __restrict__ dst1,
    ushort* __restrict__ wt, float* __restrict__ uvec, int* __restrict__ hist)
{
    const int b = blockIdx.x;
    const int t = threadIdx.x;
    if (b < WB) {                                  // W -> pre-swizzled chunks
        int idx = b * 256 + t;                     // 0..49151
        int m = idx >> 14, e = idx & 16383;
        const float* W = (m == 0) ? W0 : (m == 1) ? W1 : Wl;
        int k = e >> 7, n = e & 127;               // W[k][n]
        ushort h, l; split1(W[e], h, l);
        int q = m * 4 + (k >> 5);
        int kin8 = (k >> 3) & 3, ke = k & 7;
        int sw = n & 7;
        size_t base = (size_t)q * 8192 + n * 64;
        wt[base + (((0 | kin8) ^ sw) << 3) + ke] = h;
        wt[base + (((4 | kin8) ^ sw) << 3) + ke] = l;
    } else if (b < WB + BKB) {                     // per-chunk bucket histogram
        __shared__ int cnt[NBUCK];
        int hb = b - WB;                           // 0..195
        int rel = hb >= NBLK;
        int ci = hb - rel * NBLK;
        const int* __restrict__ dstA = rel ? dst1 : dst0;
        if (t < NBUCK) cnt[t] = 0;
        __syncthreads();
        int lo = ci * CH, hi = min(lo + CH, EE);
        for (int i = lo + t; i < hi; i += 256)
            atomicAdd(&cnt[dstA[i] >> BSH], 1);
        __syncthreads();
        if (t < NBUCK)
            hist[((rel * NBUCK) + t) * NBLK + ci] = cnt[t];
    } else {                                       // uvec: 2048 entries
        #pragma unroll
        for (int j = 0; j < 8; ++j) {
            int idx = t * 8 + j;
            int v = idx >> 7, k = idx & 127;
            int rel = v >> 3, lr = (v >> 2) & 1, h = v & 3;
            const float* W = rel ? W1 : W0;
            const float* a = rel ? (lr ? ar1 : al1) : (lr ? ar0 : al0);
            float s = 0.f;
            for (int d2 = 0; d2 < 32; ++d2)
                s += W[k * 128 + h * 32 + d2] * a[h * 32 + d2];
            uvec[v * 128 + k] = s;
        }
    }
}

// ---------------- flat exclusive scan of hist -> base -------------------------
__global__ __launch_bounds__(256) void scan_kernel(
    const int* __restrict__ hist, int* __restrict__ base)
{
    __shared__ int wq[4];
    const int t = threadIdx.x;
    const int lane = t & 63, wv = t >> 6;
    const int st = t * 76;
    const int en = min(st + 76, NSEG);
    int sum = 0;
    for (int i = st; i < en; ++i) sum += hist[i];
    int incl = sum;
    #pragma unroll
    for (int off = 1; off < 64; off <<= 1) {
        int u = __shfl_up(incl, off);
        if (lane >= off) incl += u;
    }
    if (lane == 63) wq[wv] = incl;
    __syncthreads();
    int woff = 0;
    #pragma unroll
    for (int w = 0; w < 4; ++w) woff += (w < wv) ? wq[w] : 0;
    int run = woff + incl - sum;                   // exclusive prefix
    for (int i = st; i < en; ++i) { base[i] = run; run += hist[i]; }
}

// ---------------- fused: bucket scatter (0..195) + elr (196..3320) ------------
__global__ __launch_bounds__(256) void bucketelr_kernel(
    const int* __restrict__ src0, const int* __restrict__ dst0,
    const int* __restrict__ src1, const int* __restrict__ dst1,
    const int* __restrict__ base, unsigned int* __restrict__ pk,
    const float* __restrict__ x, const float* __restrict__ uvec,
    float* __restrict__ el0, float* __restrict__ er0,
    float* __restrict__ el1, float* __restrict__ er1)
{
    __shared__ float sm[2048];                    // elr: uvec copy; bucket: ints
    const int t = threadIdx.x;

    if (blockIdx.x < BKB) {
        // ------------- bucket scatter -------------
        int* cnt = (int*)sm;
        int* bs  = cnt + 128;
        const int hb = blockIdx.x;
        const int rel = hb >= NBLK;
        const int ci = hb - rel * NBLK;
        const int* __restrict__ srcA = rel ? src1 : src0;
        const int* __restrict__ dstA = rel ? dst1 : dst0;
        if (t < NBUCK) {
            cnt[t] = 0;
            bs[t] = base[((rel * NBUCK) + t) * NBLK + ci];
        }
        __syncthreads();
        int lo = ci * CH, hi = min(lo + CH, EE);
        for (int i = lo + t; i < hi; i += 256) {
            int dd = dstA[i], ss = srcA[i];
            int bk = dd >> BSH;
            int rk = atomicAdd(&cnt[bk], 1);
            pk[bs[bk] + rk] = (unsigned int)ss | ((unsigned int)(dd & 511) << 17);
        }
        return;
    }

    // ------------- elr: el/er = x . uvec -------------
    for (int i = t; i < 2048; i += 256) sm[i] = uvec[i];
    __syncthreads();
    const int lane = t & 63, wave = t >> 6;
    const int l16 = lane & 15;
    const int r = (blockIdx.x - BKB) * 16 + wave * 4 + (lane >> 4);
    float xr[8];
    if (r < NN) {
        float4 a = *(const float4*)&x[(size_t)r * DD + l16 * 8];
        float4 b2 = *(const float4*)&x[(size_t)r * DD + l16 * 8 + 4];
        xr[0] = a.x; xr[1] = a.y; xr[2] = a.z; xr[3] = a.w;
        xr[4] = b2.x; xr[5] = b2.y; xr[6] = b2.z; xr[7] = b2.w;
    } else {
        #pragma unroll
        for (int j = 0; j < 8; ++j) xr[j] = 0.f;
    }
    float s[16];
    #pragma unroll
    for (int v = 0; v < 16; ++v) {
        float acc = 0.f;
        const float* u = &sm[v * 128 + l16 * 8];
        #pragma unroll
        for (int j = 0; j < 8; ++j) acc += xr[j] * u[j];
        s[v] = acc;
    }
    #pragma unroll
    for (int m = 1; m < 16; m <<= 1)
        #pragma unroll
        for (int v = 0; v < 16; ++v) s[v] += __shfl_xor(s[v], m);
    if (r < NN) {
        float val = s[0];
        #pragma unroll
        for (int v = 1; v < 16; ++v) val = (l16 == v) ? s[v] : val;
        float* p = (l16 & 8) ? ((l16 & 4) ? er1 : el1)
                             : ((l16 & 4) ? er0 : el0);
        p[(size_t)r * 4 + (l16 & 3)] = val;
    }
}

// ---------------- proj: x-direct MFMA, LDS-staged W, fb+out only --------------
__global__ __launch_bounds__(256) void proj_kernel(
    const float* __restrict__ x, const ushort* __restrict__ wt,
    const float* __restrict__ bias,
    ushort* __restrict__ fb0, ushort* __restrict__ fb1,
    float* __restrict__ out)
{
    __shared__ ushort lds[2][8192];               // 2 x 16KB W chunks
    const int t = threadIdx.x;
    const int lane = t & 63, wave = t >> 6;
    const int l15 = lane & 15, lg = lane >> 4;
    const int rb = blockIdx.x * 128 + wave * 32;

    int ra0 = rb + l15;      if (ra0 > NN - 1) ra0 = NN - 1;
    int ra1 = rb + 16 + l15; if (ra1 > NN - 1) ra1 = NN - 1;
    const int kb = lg * 8;

    // A fragments: load x f32, split to (hi,lo) bf16 in-register
    bf16x8 Ah0[4], Av0[4], Ah1[4], Av1[4];
    #pragma unroll
    for (int kc = 0; kc < 4; ++kc) {
        const float* p0 = &x[(size_t)ra0 * DD + kc * 32 + kb];
        const float* p1 = &x[(size_t)ra1 * DD + kc * 32 + kb];
        float4 f0a = *(const float4*)p0, f0b = *(const float4*)(p0 + 4);
        float4 f1a = *(const float4*)p1, f1b = *(const float4*)(p1 + 4);
        float t0[8] = {f0a.x, f0a.y, f0a.z, f0a.w, f0b.x, f0b.y, f0b.z, f0b.w};
        float t1[8] = {f1a.x, f1a.y, f1a.z, f1a.w, f1b.x, f1b.y, f1b.z, f1b.w};
        union { bf16x8 v; ushort u[8]; } H0, L0, H1, L1;
        #pragma unroll
        for (int j = 0; j < 8; ++j) {
            split1(t0[j], H0.u[j], L0.u[j]);
            split1(t1[j], H1.u[j], L1.u[j]);
        }
        Ah0[kc] = H0.v; Av0[kc] = L0.v;
        Ah1[kc] = H1.v; Av1[kc] = L1.v;
    }

    {   // prologue: stage chunk 0 into lds[0]
        const bf16x8* g = (const bf16x8*)wt;
        bf16x8* L = (bf16x8*)lds[0];
        #pragma unroll
        for (int i = 0; i < 4; ++i) L[t + i * 256] = g[t + i * 256];
    }

    for (int m = 0; m < 3; ++m) {
        f32x4 acc0[8], acc1[8];
        #pragma unroll
        for (int nt = 0; nt < 8; ++nt) {
            acc0[nt] = (f32x4){0.f, 0.f, 0.f, 0.f};
            acc1[nt] = (f32x4){0.f, 0.f, 0.f, 0.f};
        }

        #pragma unroll
        for (int kc = 0; kc < 4; ++kc) {
            const int q = m * 4 + kc;
            __syncthreads();
            bf16x8 st0, st1, st2, st3;
            const bool hasNext = (q < 11);
            if (hasNext) {
                const bf16x8* g = (const bf16x8*)(wt + (size_t)(q + 1) * 8192);
                st0 = g[t]; st1 = g[t + 256]; st2 = g[t + 512]; st3 = g[t + 768];
            }
            const ushort* __restrict__ L = lds[kc & 1];
            #pragma unroll
            for (int nt = 0; nt < 8; ++nt) {
                const int n = nt * 16 + l15;
                const int sw = n & 7;
                bf16x8 bh = *(const bf16x8*)&L[n * 64 + (((0 | lg) ^ sw) << 3)];
                bf16x8 bv = *(const bf16x8*)&L[n * 64 + (((4 | lg) ^ sw) << 3)];
                acc0[nt] = __builtin_amdgcn_mfma_f32_16x16x32_bf16(Ah0[kc], bh, acc0[nt], 0, 0, 0);
                acc0[nt] = __builtin_amdgcn_mfma_f32_16x16x32_bf16(Ah0[kc], bv, acc0[nt], 0, 0, 0);
                acc0[nt] = __builtin_amdgcn_mfma_f32_16x16x32_bf16(Av0[kc], bh, acc0[nt], 0, 0, 0);
                acc1[nt] = __builtin_amdgcn_mfma_f32_16x16x32_bf16(Ah1[kc], bh, acc1[nt], 0, 0, 0);
                acc1[nt] = __builtin_amdgcn_mfma_f32_16x16x32_bf16(Ah1[kc], bv, acc1[nt], 0, 0, 0);
                acc1[nt] = __builtin_amdgcn_mfma_f32_16x16x32_bf16(Av1[kc], bh, acc1[nt], 0, 0, 0);
            }
            if (hasNext) {
                bf16x8* Lw = (bf16x8*)lds[(kc & 1) ^ 1];
                Lw[t] = st0; Lw[t + 256] = st1; Lw[t + 512] = st2; Lw[t + 768] = st3;
            }
        }

        if (m < 2) {                               // feat -> bf16 tables
            ushort* __restrict__ fb = m ? fb1 : fb0;
            #pragma unroll
            for (int tt = 0; tt < 2; ++tt)
                #pragma unroll
                for (int nt = 0; nt < 8; ++nt) {
                    const int col = nt * 16 + l15;
                    #pragma unroll
                    for (int r = 0; r < 4; ++r) {
                        const int row = rb + tt * 16 + lg * 4 + r;
                        const float v = tt ? acc1[nt][r] : acc0[nt][r];
                        if (row < NN) {
                            __hip_bfloat16 hb = __float2bfloat16(v);
                            fb[(size_t)row * DD + col] = *(ushort*)&hb;
                        }
                    }
                }
        } else {                                   // out = x@Wl + bias
            #pragma unroll
            for (int tt = 0; tt < 2; ++tt)
                #pragma unroll
                for (int nt = 0; nt < 8; ++nt) {
                    const int col = nt * 16 + l15;
                    const float bv = bias[col];
                    #pragma unroll
                    for (int r = 0; r < 4; ++r) {
                        const int row = rb + tt * 16 + lg * 4 + r;
                        const float v = tt ? acc1[nt][r] : acc0[nt][r];
                        if (row < NN) out[(size_t)row * DD + col] = v + bv;
                    }
                }
        }
    }
}

// ---------------- per-bucket counting sort -> CSR row + list (lean) -----------
__global__ __launch_bounds__(256) void sort_kernel(
    const unsigned int* __restrict__ pk, const int* __restrict__ base,
    int* __restrict__ row0, int* __restrict__ row1, int* __restrict__ list)
{
    __shared__ int cnt[512];
    __shared__ int offs[512];
    __shared__ int wq[4];
    const int hb = blockIdx.x;
    const int t = threadIdx.x;
    const int lane = t & 63, wv = t >> 6;
    const int rel = hb >= NBUCK;
    const int bk = hb - rel * NBUCK;

    const int fs = base[((rel * NBUCK) + bk) * NBLK];
    const int fe = (rel == 1 && bk == NBUCK - 1) ? 2 * EE
                 : base[((rel * NBUCK) + bk + 1) * NBLK];

    cnt[t] = 0; cnt[t + 256] = 0;
    __syncthreads();
    for (int i = fs + t; i < fe; i += 256)
        atomicAdd(&cnt[pk[i] >> 17], 1);
    __syncthreads();

    int a = cnt[2 * t], bvl = cnt[2 * t + 1];
    int ps = a + bvl;
    int incl = ps;
    #pragma unroll
    for (int off = 1; off < 64; off <<= 1) {
        int u = __shfl_up(incl, off);
        if (lane >= off) incl += u;
    }
    if (lane == 63) wq[wv] = incl;
    __syncthreads();
    int woff = 0;
    #pragma unroll
    for (int w = 0; w < 4; ++w) woff += (w < wv) ? wq[w] : 0;
    int excl = woff + incl - ps;
    offs[2 * t] = excl;
    offs[2 * t + 1] = excl + a;
    __syncthreads();

    int* __restrict__ row = rel ? row1 : row0;
    const int fsLocal = fs - (rel ? EE : 0);
    const int d0 = bk << BSH;
    for (int j = t; j < 512; j += 256) {
        int d = d0 + j;
        if (d < NN) row[d] = fsLocal + offs[j] + cnt[j];
    }
    __syncthreads();

    for (int i = fs + t; i < fe; i += 256) {
        unsigned int u = pk[i];
        int ld = u >> 17;
        int p = atomicAdd(&offs[ld], 1);
        list[fs + p] = (int)(u & 0x1FFFF);
    }
}

// ---------------- aggregate: wave per dst, 2-deep pipelined gather ------------
__global__ __launch_bounds__(256) void agg_kernel(
    const int* __restrict__ row0, const int* __restrict__ list0,
    const float* __restrict__ el0, const float* __restrict__ er0,
    const int* __restrict__ row1, const int* __restrict__ list1,
    const float* __restrict__ el1, const float* __restrict__ er1,
    const ushort* __restrict__ fb0, const ushort* __restrict__ fb1,
    float* __restrict__ out)
{
    const int d = blockIdx.x * 4 + (threadIdx.x >> 6);
    const int lane = threadIdx.x & 63;
    if (d >= NN) return;
    const int g = lane >> 4;             // 4 edge slots, 2-deep pipeline
    const int l16 = lane & 15;
    const int c = l16 * 8;               // 8 output cols per lane
    const int h = l16 >> 2;              // head = col>>5

    float tot[8] = {0.f, 0.f, 0.f, 0.f, 0.f, 0.f, 0.f, 0.f};

    #pragma unroll
    for (int rel = 0; rel < 2; ++rel) {
        const int* __restrict__ rowA = rel ? row1 : row0;
        const int* __restrict__ lst  = rel ? list1 : list0;
        const float* __restrict__ elA = rel ? el1 : el0;
        const float* __restrict__ erA = rel ? er1 : er0;
        const ushort* __restrict__ fbA = rel ? fb1 : fb0;

        const int s0 = d ? rowA[d - 1] : 0, e0 = rowA[d];
        const float erh = erA[(size_t)d * 4 + h];
        float acc[8] = {0.f, 0.f, 0.f, 0.f, 0.f, 0.f, 0.f, 0.f};
        float den = 0.f;

        int i = s0 + g;
        float elvA = 0.f;
        ushrt8 fA = (ushrt8){0, 0, 0, 0, 0, 0, 0, 0};
        if (i < e0) {
            int s = lst[i];
            elvA = elA[(size_t)s * 4 + h];
            fA = *(const ushrt8*)&fbA[(size_t)s * DD + c];
        }
        while (i < e0) {
            const int inext = i + 4;
            float elvB = 0.f;
            ushrt8 fB = (ushrt8){0, 0, 0, 0, 0, 0, 0, 0};
            if (inext < e0) {
                int s = lst[inext];
                elvB = elA[(size_t)s * 4 + h];
                fB = *(const ushrt8*)&fbA[(size_t)s * DD + c];
            }
            float ev = elvA + erh;
            ev = ev > 0.f ? ev : NEG_SLOPE * ev;
            float w = __expf(ev);
            den += w;
            #pragma unroll
            for (int q = 0; q < 8; ++q) acc[q] += w * bf2f(fA[q]);
            i = inext; elvA = elvB; fA = fB;
        }

        den += __shfl_xor(den, 16); den += __shfl_xor(den, 32);
        #pragma unroll
        for (int q = 0; q < 8; ++q) {
            acc[q] += __shfl_xor(acc[q], 16);
            acc[q] += __shfl_xor(acc[q], 32);
        }
        if (e0 > s0) {
            float inv = 1.f / den;
            #pragma unroll
            for (int q = 0; q < 8; ++q) tot[q] += acc[q] * inv;
        }
    }

    if (g == 0) {
        float4 o1 = *(float4*)&out[(size_t)d * DD + c];
        float4 o2 = *(float4*)&out[(size_t)d * DD + c + 4];
        o1.x = fmaxf(o1.x + tot[0], 0.f); o1.y = fmaxf(o1.y + tot[1], 0.f);
        o1.z = fmaxf(o1.z + tot[2], 0.f); o1.w = fmaxf(o1.w + tot[3], 0.f);
        o2.x = fmaxf(o2.x + tot[4], 0.f); o2.y = fmaxf(o2.y + tot[5], 0.f);
        o2.z = fmaxf(o2.z + tot[6], 0.f); o2.w = fmaxf(o2.w + tot[7], 0.f);
        *(float4*)&out[(size_t)d * DD + c] = o1;
        *(float4*)&out[(size_t)d * DD + c + 4] = o2;
    }
}

extern "C" void kernel_launch(void* const* d_in, const int* in_sizes, int n_in,
                              void* d_out, int out_size, void* d_ws, size_t ws_size,
                              hipStream_t stream)
{
    const float* x    = (const float*)d_in[0];
    const float* W0   = (const float*)d_in[1];
    const float* al0  = (const float*)d_in[2];
    const float* ar0  = (const float*)d_in[3];
    const float* W1   = (const float*)d_in[4];
    const float* al1  = (const float*)d_in[5];
    const float* ar1  = (const float*)d_in[6];
    const float* Wl   = (const float*)d_in[7];
    const float* bias = (const float*)d_in[8];
    const int* src0   = (const int*)d_in[9];
    const int* dst0   = (const int*)d_in[10];
    const int* src1   = (const int*)d_in[11];
    const int* dst1   = (const int*)d_in[12];
    float* out = (float*)d_out;

    // workspace layout
    ushort* wsu = (ushort*)d_ws;
    ushort* fb0 = wsu;                          // N*128 ushorts
    ushort* fb1 = fb0 + (size_t)NN * DD;
    ushort* wt  = fb1 + (size_t)NN * DD;        // 12*8192 ushorts
    float* uvec = (float*)(wt + 12 * 8192);     // 2048 f32
    float* el0  = uvec + 2048;
    float* er0  = el0 + (size_t)NN * HH;
    float* el1  = er0 + (size_t)NN * HH;
    float* er1  = el1 + (size_t)NN * HH;
    int* hist   = (int*)(er1 + (size_t)NN * HH);
    int* base   = hist + NSEG;
    int* row0   = base + NSEG;
    int* row1   = row0 + NN;
    unsigned int* pk = (unsigned int*)(row1 + NN);    // 2*E
    int* list   = (int*)(pk + (size_t)2 * EE);        // 2*E
    int* list0  = list;
    int* list1  = list + EE;

    prep_kernel<<<dim3(WB + BKB + 1), dim3(256), 0, stream>>>(
        W0, W1, Wl, al0, ar0, al1, ar1, dst0, dst1, wt, uvec, hist);

    scan_kernel<<<dim3(1), dim3(256), 0, stream>>>(hist, base);

    bucketelr_kernel<<<dim3(BKB + ELRB), dim3(256), 0, stream>>>(
        src0, dst0, src1, dst1, base, pk, x, uvec, el0, er0, el1, er1);

    proj_kernel<<<dim3(PJB), dim3(256), 0, stream>>>(
        x, wt, bias, fb0, fb1, out);

    sort_kernel<<<dim3(SORTB), dim3(256), 0, stream>>>(
        pk, base, row0, row1, list);

    agg_kernel<<<dim3((NN + 3) / 4), dim3(256), 0, stream>>>(
        row0, list0, el0, er0, row1, list1, el1, er1, fb0, fb1, out);
}